// Round 8
// baseline (525.921 us; speedup 1.0000x reference)
//
#include <hip/hip_runtime.h>
#include <hip/hip_fp16.h>
#include <math.h>

// Problem constants (from reference)
#define B_TRAJ 16384
#define T_STEPS 60
#define D_IN 36
#define L_DIM 10
#define C_NUM 20
#define S_STAT 9
#define OUT_DIM 8
#define CH 12                 // steps per xproj chunk
#define NCHUNK 5              // 60 / 12
#define NG 16                 // trajs (groups) per 256-thread block
#define SCS 72                // scratch stride floats (72%32==8 -> staggered banks, 2-way max)

#define LOG2E 1.4426950408889634f

typedef float f32x2 __attribute__((ext_vector_type(2)));
__device__ __forceinline__ f32x2 pkfma(f32x2 a, f32x2 b, f32x2 c) {
    // llvm.fma.v2f32 -> v_pk_fma_f32 on gfx950 (full-rate packed f32)
    return __builtin_elementwise_fma(a, b, c);
}
__device__ __forceinline__ float rcp_fast(float x) { return __builtin_amdgcn_rcpf(x); }
__device__ __forceinline__ float exp2_fast(float x) { return __builtin_amdgcn_exp2f(x); }
__device__ __forceinline__ float sigm_fast(float x) {
    return rcp_fast(1.0f + exp2_fast(x * -LOG2E));
}
__device__ __forceinline__ float tanh_fast(float x) {
    const float t = fminf(fmaxf(x * (2.0f * LOG2E), -30.0f), 30.0f);
    return fmaf(-2.0f, rcp_fast(exp2_fast(t) + 1.0f), 1.0f);
}
#define WFENCE() __builtin_amdgcn_wave_barrier()

// v13 = v10's structure with the register-cap bug fixed (occupancy bet).
// 16 trajs per 256-thread block, 16 lanes/traj, v9 scan math. xproj chunked
// (CH=12) into [tt][g][col16][gate4] f16 -> one ds_read_b64 per step gives
// (u,r,n) pre-acts. Head accumulated at chunk boundaries into 1 scalar/lane.
// NO launch_bounds cap (v10 lesson: cap 64 VGPR -> 163MB spill traffic).
// Boundary weight loads laundered (opaque +0) so they cannot be hoisted into
// permanently-live registers. LDS ~34KB -> 4 blocks/CU -> 16 waves/CU.
__global__ __launch_bounds__(256)
void dgm2_v13(
    const float* __restrict__ data,        // [B, T, D]
    const float* __restrict__ time_steps,  // [T]
    const float* __restrict__ static_data, // [B, S]
    const float* __restrict__ W_update,    // [46, 10]
    const float* __restrict__ b_update,
    const float* __restrict__ W_reset,     // [46, 10]
    const float* __restrict__ b_reset,
    const float* __restrict__ W_new,       // [46, 10]
    const float* __restrict__ b_new,
    const float* __restrict__ W_emit,      // [30, 20]
    const float* __restrict__ b_emit,
    const float* __restrict__ W_ode,       // [10, 10]
    const float* __restrict__ b_ode,
    const float* __restrict__ W_mlp,       // [609, 8]
    const float* __restrict__ b_mlp,
    float* __restrict__ out)               // [B, 8]
{
    __shared__ __align__(16) __half xb[CH * NG * 16 * 4];  // 24576 B [tt][g][col16][u,r,n,pad]
    __shared__ __align__(16) __half yb[CH * NG * 12];      //  4608 B [tt][g][12] (10 used)
    __shared__ __align__(16) float  sc[NG * SCS];          //  4608 B YI@0 YR@16 Y@32 Z@48
    __shared__ float dts[T_STEPS];                         //   240 B => ~34 KB

    const int tid  = threadIdx.x;
    const int g    = tid >> 4;      // group = local traj
    const int q    = tid & 15;      // lane within group
    const int traj = blockIdx.x * NG + g;

    if (tid < T_STEPS) dts[tid] = (tid == 0) ? 0.01f : time_steps[tid] - time_steps[tid - 1];

    const bool qg = (q < 10);
    const int  qc = qg ? q : 0;     // clamped gate col (lanes 10-15: garbage-safe)

    float* gYI = sc + g * SCS;
    float* gYR = gYI + 16;
    float* gY  = gYI + 32;
    float* gZ  = gYI + 48;

    // ---- persistent per-thread state ----
    f32x2 y2[5];
#pragma unroll
    for (int k = 0; k < 5; ++k) y2[k] = (f32x2){0.0f, 0.0f};
    float yown  = 0.0f;
    float phead = 0.0f;             // MLP-head partial: col q&7, rows tt=(q>>3)+2i
    gZ[q] = 0.0f;                   // carried unnormalized z; 0 => p=0 at t=0
    if (q < 4) gZ[16 + q] = 0.0f;

    // ---- boundary: compute xproj chunk c into xb (phase-1 parallelism) ----
    // lane q -> cols c0=q (0..15), c1=16+q (q<14); col space 0-9 u, 10-19 r, 20-29 n.
    auto do_xproj = [&](int c) {
        int lz = 0;
        asm volatile("" : "+v"(lz));          // opaque 0: blocks hoist/CSE of weight loads
        const int  c0   = q;
        const bool has1 = (q < 14);
        const int  c1   = has1 ? 16 + q : 29;
        const float* W0 = (c0 < 10) ? W_update : W_reset;
        const int   cc0 = (c0 < 10) ? c0 : c0 - 10;
        const int   gt0 = (c0 < 10) ? 0 : 1;
        const float* W1 = (c1 < 20) ? W_reset : W_new;
        const int   cc1 = (c1 < 20) ? c1 - 10 : c1 - 20;
        const int   gt1 = (c1 < 20) ? 1 : 2;
        f32x2 wxp0[18], wxp1[18];             // x-part rows 10..45
#pragma unroll
        for (int j = 0; j < 18; ++j) {
            wxp0[j] = (f32x2){W0[(L_DIM + 2 * j) * L_DIM + cc0 + lz],
                              W0[(L_DIM + 2 * j + 1) * L_DIM + cc0 + lz]};
            const f32x2 v1 = (f32x2){W1[(L_DIM + 2 * j) * L_DIM + cc1 + lz],
                                     W1[(L_DIM + 2 * j + 1) * L_DIM + cc1 + lz]};
            wxp1[j] = has1 ? v1 : (f32x2){0.0f, 0.0f};
        }
        const float b0 = (c0 < 10) ? b_update[c0] : b_reset[c0 - 10];
        const float b1 = has1 ? ((c1 < 20) ? b_reset[c1 - 10] : b_new[c1 - 20]) : 0.0f;
        const float* xbase = data + ((size_t)traj * T_STEPS + c * CH) * D_IN;
#pragma unroll 1
        for (int tt = 0; tt < CH; ++tt) {
            const float* xr = xbase + tt * D_IN;
            f32x2 a0 = (f32x2){b0, 0.0f}, a1 = (f32x2){b1, 0.0f};
#pragma unroll
            for (int cq = 0; cq < 9; ++cq) {
                const float4 x4 = *reinterpret_cast<const float4*>(xr + cq * 4);
                const f32x2 xlo = (f32x2){x4.x, x4.y};
                const f32x2 xhi = (f32x2){x4.z, x4.w};
                a0 = pkfma(xlo, wxp0[2 * cq], a0);
                a0 = pkfma(xhi, wxp0[2 * cq + 1], a0);
                a1 = pkfma(xlo, wxp1[2 * cq], a1);
                a1 = pkfma(xhi, wxp1[2 * cq + 1], a1);
            }
            __half* dst = xb + (size_t)((tt * NG + g) * 16) * 4;
            dst[cc0 * 4 + gt0] = __float2half(a0.x + a0.y);
            if (has1) dst[cc1 * 4 + gt1] = __float2half(a1.x + a1.y);
        }
    };

    // ---- boundary: head partials from the chunk's y stash ----
    auto do_head = [&](int c) {
        const int col = q & 7;
#pragma unroll 1
        for (int i = 0; i < CH / 2; ++i) {
            const int tt = (q >> 3) + 2 * i;
            const int t  = c * CH + tt;
            const __half2* yrow = reinterpret_cast<const __half2*>(yb + (tt * NG + g) * 12);
            const float* wr = W_mlp + (size_t)t * (L_DIM * OUT_DIM) + col;
#pragma unroll
            for (int k2 = 0; k2 < 5; ++k2) {
                const float2 yv = __half22float2(yrow[k2]);
                phead = fmaf(yv.x, wr[(2 * k2) * OUT_DIM], phead);
                phead = fmaf(yv.y, wr[(2 * k2 + 1) * OUT_DIM], phead);
            }
        }
    };

    auto ldvec = [&](const float* p, f32x2* d) {
        const float4 a = *reinterpret_cast<const float4*>(p);
        const float4 b = *reinterpret_cast<const float4*>(p + 4);
        const float2 c = *reinterpret_cast<const float2*>(p + 8);
        d[0] = (f32x2){a.x, a.y}; d[1] = (f32x2){a.z, a.w};
        d[2] = (f32x2){b.x, b.y}; d[3] = (f32x2){b.z, b.w};
        d[4] = (f32x2){c.x, c.y};
    };

    // ---- scan weights (loaded once; small per-lane footprint as in v9) ----
    f32x2 wode2[5], wu2[5], wr2[5], wn2[5];
#pragma unroll
    for (int j = 0; j < 5; ++j) {
        if (qg) {
            wode2[j] = (f32x2){W_ode[(2 * j) * L_DIM + q], W_ode[(2 * j + 1) * L_DIM + q]};
            wu2[j]   = (f32x2){W_update[(2 * j) * L_DIM + q], W_update[(2 * j + 1) * L_DIM + q]};
            wr2[j]   = (f32x2){W_reset[(2 * j) * L_DIM + q], W_reset[(2 * j + 1) * L_DIM + q]};
            wn2[j]   = (f32x2){W_new[(2 * j) * L_DIM + q], W_new[(2 * j + 1) * L_DIM + q]};
        } else {
            wode2[j] = wu2[j] = wr2[j] = wn2[j] = (f32x2){0.0f, 0.0f};
        }
    }
    const float bode = qg ? b_ode[q] : 0.0f;
    const int  e0  = q;
    const bool he1 = (q < 4);
    const int  e1  = he1 ? 16 + q : 19;
    f32x2 wez0[10], wez1[10], wey0[5], wey1[5];
#pragma unroll
    for (int j = 0; j < 10; ++j) {
        wez0[j] = (f32x2){W_emit[(2 * j) * C_NUM + e0], W_emit[(2 * j + 1) * C_NUM + e0]};
        const f32x2 v1 = (f32x2){W_emit[(2 * j) * C_NUM + e1], W_emit[(2 * j + 1) * C_NUM + e1]};
        wez1[j] = he1 ? v1 : (f32x2){0.0f, 0.0f};
    }
#pragma unroll
    for (int j = 0; j < 5; ++j) {
        wey0[j] = (f32x2){W_emit[(C_NUM + 2 * j) * C_NUM + e0],
                          W_emit[(C_NUM + 2 * j + 1) * C_NUM + e0]};
        const f32x2 v1 = (f32x2){W_emit[(C_NUM + 2 * j) * C_NUM + e1],
                                 W_emit[(C_NUM + 2 * j + 1) * C_NUM + e1]};
        wey1[j] = he1 ? v1 : (f32x2){0.0f, 0.0f};
    }
    const float be0 = b_emit[e0];
    const float be1 = he1 ? b_emit[e1] : 0.0f;

    do_xproj(0);
    __syncthreads();

#pragma unroll 1
    for (int c = 0; c < NCHUNK; ++c) {
        // ---- scan CH steps (wave-local sync only) ----
#pragma unroll 1
        for (int tt = 0; tt < CH; ++tt) {
            const int t = c * CH + tt;
            const float dt = dts[t];

            // ODE (lane-local col): yi_q = y_q + tanh(b + y.Wode[:,q])*dt
            f32x2 g2 = (f32x2){bode, 0.0f};
#pragma unroll
            for (int k = 0; k < 5; ++k) g2 = pkfma(y2[k], wode2[k], g2);
            const float yis = fmaf(tanh_fast(g2.x + g2.y), dt, yown);
            gYI[q] = yis;
            WFENCE();
            f32x2 yi2[5];
            ldvec(gYI, yi2);

            // xproj: one b64 -> (u,r,n,pad) pre-activations for col q (bias folded)
            union { float2 f2; __half2 h2[2]; } xu;
            xu.f2 = *reinterpret_cast<const float2*>(xb + (size_t)((tt * NG + g) * 16 + qc) * 4);
            const float2 x01 = __half22float2(xu.h2[0]);   // (u, r)
            const float2 x23 = __half22float2(xu.h2[1]);   // (n, junk)

            f32x2 au2 = (f32x2){x01.x, 0.0f};
            f32x2 ar2 = (f32x2){x01.y, 0.0f};
#pragma unroll
            for (int k = 0; k < 5; ++k) {
                au2 = pkfma(yi2[k], wu2[k], au2);
                ar2 = pkfma(yi2[k], wr2[k], ar2);
            }
            const float u = sigm_fast(au2.x + au2.y);
            const float r = sigm_fast(ar2.x + ar2.y);
            gYR[q] = r * yis;
            WFENCE();
            f32x2 yr2[5];
            ldvec(gYR, yr2);

            // candidate + blend (lane-local)
            f32x2 an2 = (f32x2){x23.x, 0.0f};
#pragma unroll
            for (int k = 0; k < 5; ++k) an2 = pkfma(yr2[k], wn2[k], an2);
            const float nv = an2.x + an2.y;
            const float yn = fmaf(u, yis - nv, nv);
            yown = yn;
            gY[q] = yn;
            if (qg) yb[(tt * NG + g) * 12 + q] = __float2half(yn);   // stash for head
            WFENCE();
            ldvec(gY, y2);

            // emitter: logit_c = b_c + (z_prev . We_p[:,c])/sum(z) + y . We_y[:,c]
            f32x2 zz[10];
#pragma unroll
            for (int j = 0; j < 5; ++j) {
                const float4 z = *reinterpret_cast<const float4*>(gZ + j * 4);
                zz[2 * j] = (f32x2){z.x, z.y}; zz[2 * j + 1] = (f32x2){z.z, z.w};
            }
            f32x2 zd0 = (f32x2){0.0f, 0.0f}, zd1 = (f32x2){0.0f, 0.0f};
            f32x2 zs2 = (f32x2){0.0f, 0.0f};
#pragma unroll
            for (int j = 0; j < 10; ++j) {
                zd0 = pkfma(zz[j], wez0[j], zd0);
                zd1 = pkfma(zz[j], wez1[j], zd1);
                zs2 = zs2 + zz[j];
            }
            const float pinv = (t == 0) ? 0.0f : rcp_fast(zs2.x + zs2.y);
            f32x2 ev0 = (f32x2){fmaf(zd0.x + zd0.y, pinv, be0), 0.0f};
            f32x2 ev1 = (f32x2){fmaf(zd1.x + zd1.y, pinv, be1), 0.0f};
#pragma unroll
            for (int k = 0; k < 5; ++k) {
                ev0 = pkfma(y2[k], wey0[k], ev0);
                ev1 = pkfma(y2[k], wey1[k], ev1);
            }
            gZ[q] = exp2_fast(fminf((ev0.x + ev0.y) * LOG2E, 86.0f));
            if (he1) gZ[16 + q] = exp2_fast(fminf((ev1.x + ev1.y) * LOG2E, 86.0f));
            // no trailing fence: next step's fences precede the z read.
        }

        __syncthreads();
        do_head(c);                          // reads yb (chunk c)
        if (c + 1 < NCHUNK) do_xproj(c + 1); // writes xb (chunk c+1)
        __syncthreads();
    }

    // ---- epilogue: combine head halves, add static part ----
    phead += __shfl_xor(phead, 8, 16);
    if (q < OUT_DIM) {
        const float* stp = static_data + (size_t)traj * S_STAT;
        const float* wms = W_mlp + (size_t)(T_STEPS * L_DIM) * OUT_DIM;
        float o = phead;
#pragma unroll
        for (int i = 0; i < S_STAT; ++i) o += stp[i] * wms[i * OUT_DIM + q];
        out[(size_t)traj * OUT_DIM + q] = o + b_mlp[q];
    }
}

extern "C" void kernel_launch(void* const* d_in, const int* in_sizes, int n_in,
                              void* d_out, int out_size, void* d_ws, size_t ws_size,
                              hipStream_t stream) {
    const float* data        = (const float*)d_in[0];
    const float* time_steps  = (const float*)d_in[1];
    const float* static_data = (const float*)d_in[2];
    const float* W_update    = (const float*)d_in[3];
    const float* b_update    = (const float*)d_in[4];
    const float* W_reset     = (const float*)d_in[5];
    const float* b_reset     = (const float*)d_in[6];
    const float* W_new       = (const float*)d_in[7];
    const float* b_new       = (const float*)d_in[8];
    const float* W_emit      = (const float*)d_in[9];
    const float* b_emit      = (const float*)d_in[10];
    const float* W_ode       = (const float*)d_in[11];
    const float* b_ode       = (const float*)d_in[12];
    const float* W_mlp       = (const float*)d_in[13];
    const float* b_mlp       = (const float*)d_in[14];
    float* out = (float*)d_out;

    // 16 trajectories per 256-thread block -> 1024 blocks, 4096 waves
    dim3 grid(B_TRAJ / NG), block(256);
    hipLaunchKernelGGL(dgm2_v13, grid, block, 0, stream,
                       data, time_steps, static_data,
                       W_update, b_update, W_reset, b_reset, W_new, b_new,
                       W_emit, b_emit, W_ode, b_ode, W_mlp, b_mlp, out);
}